// Round 1
// baseline (226.490 us; speedup 1.0000x reference)
//
#include <hip/hip_runtime.h>

// RoPE: X (L=2048, D=4096, N=4) fp32 -> out same shape.
// Round 4: kernel was VALU-bound (1.2 TB/s effective vs 6.3 TB/s achievable).
// Two transcendental sinks removed:
//  1) fp64 pow per element -> hoisted to once per THREAD via grid-stride whose
//     stride (2048 blocks * 256 thr = 524288 = 256 full rows) keeps j fixed,
//     so theta (depends only on j) is computed once and reused 8x.
//     Exact same expression as the previously-passing kernel -> identical theta,
//     identical ang = fl32((l+1)*theta) -> identical rounding behavior.
//  2) sincosf Payne-Hanek slow path (|ang| up to ~2e7 > 2^23) -> replaced by an
//     explicit double-precision mod-2pi reduction (hi/lo split, error ~1e-9 rad),
//     then sincosf on |r| <= pi which always takes the cheap small-arg path.
//     Output differs from sincosf(ang) by <~2e-7, negligible vs absmax 0.03125.

#define L_DIM 2048
#define D_DIM 4096
#define HALF 2048
#define NTHREADS 256
#define NBLOCKS 2048
#define ITERS 8   // (L_DIM*HALF) / (NBLOCKS*NTHREADS)

__global__ __launch_bounds__(256) void rope_kernel(const float4* __restrict__ X,
                                                   float4* __restrict__ out) {
    int tid = blockIdx.x * NTHREADS + threadIdx.x;   // 0 .. 524287
    int j  = tid & (HALF - 1);   // fixed per thread across all iterations
    int l0 = tid >> 11;          // 0 .. 255

    // theta: once per thread (was once per element). Same double->float path
    // as the passing kernel: correctly-rounded f32 of 10000^(j/2048).
    double e = (double)j * (1.0 / 2048.0);
    float theta = (float)pow(10000.0, e);

    #pragma unroll
    for (int k = 0; k < ITERS; ++k) {
        int l = l0 + (k << 8);             // j fixed, l walks 256-row strides
        int base = l * D_DIM + j;          // float4 index of x1

        // Issue loads before the sincos dependency chain.
        float4 x1 = X[base];
        float4 x2 = X[base + HALF];

        // Single f32 multiply, exactly as the reference rounds ang.
        float pos = (float)(l + 1);
        float ang = pos * theta;

        // Double-precision reduction mod 2*pi. ang is exact as a double;
        // q <= ~3.4e6, hi/lo split of 2*pi keeps |error| ~1e-9 rad.
        double ad = (double)ang;
        double q  = rint(ad * 1.5915494309189534e-1);       // 1/(2*pi)
        double r  = fma(-q, 6.283185307179586, ad);          // 2*pi hi
        r         = fma(-q, 2.4492935982947064e-16, r);      // 2*pi lo
        float rf  = (float)r;                                // |rf| <= pi

        float s, c;
        sincosf(rf, &s, &c);   // small-arg fast path only

        float4 o1, o2;
        o1.x = c * x1.x - s * x2.x;
        o1.y = c * x1.y - s * x2.y;
        o1.z = c * x1.z - s * x2.z;
        o1.w = c * x1.w - s * x2.w;
        o2.x = s * x1.x + c * x2.x;
        o2.y = s * x1.y + c * x2.y;
        o2.z = s * x1.z + c * x2.z;
        o2.w = s * x1.w + c * x2.w;

        out[base] = o1;
        out[base + HALF] = o2;
    }
}

extern "C" void kernel_launch(void* const* d_in, const int* in_sizes, int n_in,
                              void* d_out, int out_size, void* d_ws, size_t ws_size,
                              hipStream_t stream) {
    const float4* X = (const float4*)d_in[0];
    float4* out = (float4*)d_out;
    rope_kernel<<<dim3(NBLOCKS), dim3(NTHREADS), 0, stream>>>(X, out);
}

// Round 3
// 218.438 us; speedup vs baseline: 1.0369x; 1.0369x over previous
//
#include <hip/hip_runtime.h>

// RoPE: X (L=2048, D=4096, N=4) fp32 -> out same shape.
// Round 6 (3rd in session). Round-5 kernel failed to COMPILE only:
// __builtin_nontemporal_load/store reject HIP_vector_type<float,4>.
// Fix: native clang ext_vector_type(4) alias for all global traffic.
// Theory unchanged (untested round 5):
//  - kernel is memory-bound (268MB @ 6.3TB/s = 42.6us floor); rocprof top-5
//    shows only ~80us 512MiB poison fills, so dur_us ~220 is mostly harness.
//  - 2 rows/thread, 8192 blocks, all 4 loads issued before sincos chain,
//    nontemporal ld/st (every byte touched once -> skip L2 allocation).
// Numerics identical to passing rounds: per-thread double pow theta,
// ang = fl32((l+1)*theta), fp64 mod-2pi reduction (~1e-9 rad), small-arg
// sincosf. absmax must stay 0.03125.

#define L_DIM 2048
#define D_DIM 4096   // float4 elements per row (N=4 folded into one vec4)
#define HALF 2048
#define NTHREADS 256
#define NBLOCKS 8192
// threads = 2,097,152 = L*HALF/2; each thread does rows lA and lA+1024

typedef float floatx4 __attribute__((ext_vector_type(4)));

__device__ __forceinline__ void rot_pair(float ang, floatx4 x1, floatx4 x2,
                                         floatx4& o1, floatx4& o2) {
    // fp64 reduction mod 2*pi: ang exact as double, q <= ~3.4e6,
    // hi/lo split of 2*pi -> |err| ~1e-9 rad; then small-arg sincosf.
    double ad = (double)ang;
    double q  = rint(ad * 1.5915494309189534e-1);       // 1/(2*pi)
    double r  = fma(-q, 6.283185307179586, ad);          // 2*pi hi
    r         = fma(-q, 2.4492935982947064e-16, r);      // 2*pi lo
    float rf  = (float)r;

    float s, c;
    sincosf(rf, &s, &c);

    o1 = c * x1 - s * x2;   // ext_vector_type: elementwise ops
    o2 = s * x1 + c * x2;
}

__global__ __launch_bounds__(256) void rope_kernel(const floatx4* __restrict__ X,
                                                   floatx4* __restrict__ out) {
    int tid = blockIdx.x * NTHREADS + threadIdx.x;   // 0 .. 2097151
    int j  = tid & (HALF - 1);    // fixed per thread
    int lA = tid >> 11;           // 0 .. 1023
    int lB = lA + 1024;

    int bA = lA * D_DIM + j;      // vec4 index of x1, row A
    int bB = lB * D_DIM + j;      // row B

    // Issue all 4 stream loads before any math (nontemporal: no reuse).
    floatx4 x1a = __builtin_nontemporal_load(&X[bA]);
    floatx4 x2a = __builtin_nontemporal_load(&X[bA + HALF]);
    floatx4 x1b = __builtin_nontemporal_load(&X[bB]);
    floatx4 x2b = __builtin_nontemporal_load(&X[bB + HALF]);

    // theta once per thread: correctly-rounded f32 of 10000^(j/2048),
    // same expression as the passing kernels (absmax anchor).
    double e = (double)j * (1.0 / 2048.0);
    float theta = (float)pow(10000.0, e);

    float angA = (float)(lA + 1) * theta;   // single f32 multiply, as reference
    float angB = (float)(lB + 1) * theta;

    floatx4 o1a, o2a, o1b, o2b;
    rot_pair(angA, x1a, x2a, o1a, o2a);
    rot_pair(angB, x1b, x2b, o1b, o2b);

    __builtin_nontemporal_store(o1a, &out[bA]);
    __builtin_nontemporal_store(o2a, &out[bA + HALF]);
    __builtin_nontemporal_store(o1b, &out[bB]);
    __builtin_nontemporal_store(o2b, &out[bB + HALF]);
}

extern "C" void kernel_launch(void* const* d_in, const int* in_sizes, int n_in,
                              void* d_out, int out_size, void* d_ws, size_t ws_size,
                              hipStream_t stream) {
    const floatx4* X = (const floatx4*)d_in[0];
    floatx4* out = (floatx4*)d_out;
    rope_kernel<<<dim3(NBLOCKS), dim3(NTHREADS), 0, stream>>>(X, out);
}